// Round 1
// baseline (219.419 us; speedup 1.0000x reference)
//
#include <hip/hip_runtime.h>

// Problem constants: bs=16384, C=10000, M=6, D=256
constexpr int kBS = 16384;
constexpr int kC  = 10000;
constexpr int kM  = 6;
constexpr int kD  = 256;
constexpr float kEPS = 1e-4f;
constexpr int kNPart = 256;   // loss partial slots (low-contention atomics)

// ---------- Kernel 1: per-label histogram -----------------------------------
__global__ __launch_bounds__(256) void k_count(
    const int* __restrict__ labels,   // [BS]
    int* __restrict__ offs)           // ws: [C], pre-zeroed
{
    const int row = blockIdx.x * 256 + threadIdx.x;
    if (row < kBS) atomicAdd(offs + labels[row], 1);
}

// ---------- Kernel 2: exclusive prefix scan over counts (single block) ------
// 256 threads x 40 contiguous labels each (10240 >= 10000).
__global__ __launch_bounds__(256) void k_scan(int* __restrict__ offs)
{
    __shared__ int wsum[4];
    const int t    = threadIdx.x;
    const int lane = t & 63;
    const int wid  = t >> 6;
    const int base = t * 40;

    int v[40];
    int s = 0;
#pragma unroll
    for (int i = 0; i < 40; ++i) {
        const int idx = base + i;
        v[i] = (idx < kC) ? offs[idx] : 0;
        s += v[i];
    }
    // inclusive wave scan of per-thread sums
    int incl = s;
#pragma unroll
    for (int off = 1; off < 64; off <<= 1) {
        const int o = __shfl_up(incl, off, 64);
        if (lane >= off) incl += o;
    }
    if (lane == 63) wsum[wid] = incl;
    __syncthreads();
    int wpre = 0;
    for (int w = 0; w < wid; ++w) wpre += wsum[w];

    int run = wpre + incl - s;        // exclusive prefix at this thread's base
#pragma unroll
    for (int i = 0; i < 40; ++i) {
        const int idx = base + i;
        if (idx < kC) offs[idx] = run;
        run += v[i];
    }
}

// ---------- Kernel 3: scatter rows into CSR order ---------------------------
// Bumps offs[lab]; afterwards offs[lab] == inclusive_prefix[lab] == end[lab],
// so k_agg reads start = offs[lab-1], end = offs[lab].
__global__ __launch_bounds__(256) void k_scatter(
    const int* __restrict__ labels,
    int* __restrict__ offs,
    int* __restrict__ order)          // ws: [BS]
{
    const int row = blockIdx.x * 256 + threadIdx.x;
    if (row < kBS) {
        const int pos = atomicAdd(offs + labels[row], 1);
        order[pos] = row;
    }
}

// ---------- Kernel 4: main aggregation — one block per label ----------------
// 256 threads; thread owns element d = threadIdx.x of every M-row.
// All waves iterate the label's CSR segment (independent loads, no chase).
__global__ __launch_bounds__(256) void k_agg(
    const float* __restrict__ data,     // [BS, D]
    const float* __restrict__ beta,     // [BS]
    const int*   __restrict__ offs,     // ws: [C] (post-scatter: end offsets)
    const int*   __restrict__ order,    // ws: [BS]
    const float* __restrict__ W1,       // [M, C]
    const float* __restrict__ b1,       // [M]
    const float* __restrict__ W2,       // [M, M]
    const float* __restrict__ b2,       // [M]
    const float* __restrict__ centers,  // [C*M, D]
    const float* __restrict__ memory,   // [C*M, D]
    const float* __restrict__ memw,     // [C*M]
    float* __restrict__ partial,        // ws: [kNPart], pre-zeroed
    float* __restrict__ sum_v,          // [BS, M]
    float* __restrict__ mem_out,        // [C*M, D]
    float* __restrict__ mw_out)         // [C*M]
{
    __shared__ float ls[4];
    const int lab  = blockIdx.x;
    const int tid  = threadIdx.x;
    const int lane = tid & 63;
    const int wid  = tid >> 6;
    const size_t cbase = (size_t)lab * (kM * kD) + tid;

    const int start = (lab == 0) ? 0 : offs[lab - 1];
    const int end   = offs[lab];

    // prefetch this label's centers & memory elements (independent loads)
    float cv[kM], mv[kM];
#pragma unroll
    for (int m = 0; m < kM; ++m) {
        cv[m] = centers[cbase + (size_t)m * kD];
        mv[m] = memory [cbase + (size_t)m * kD];
    }

    // per-label MLP head -> column_sum (uniform across the block)
    float csarr[kM];
    {
        float h[kM];
#pragma unroll
        for (int m = 0; m < kM; ++m) {
            const float vv = W1[m * kC + lab] + b1[m];
            h[m] = vv > 0.f ? vv : 0.f;
        }
        float cs = 0.f;
#pragma unroll
        for (int m = 0; m < kM; ++m) {
            float z = b2[m];
#pragma unroll
            for (int j = 0; j < kM; ++j) z += W2[m * kM + j] * h[j];
            cs += 1.f / (1.f + expf(-z)) + kEPS;
            csarr[m] = cs;
        }
    }
    // tid-indexed csarr for sum_v writes (threads 0..5)
    float csel = csarr[0];
    csel = (tid == 1) ? csarr[1] : csel;
    csel = (tid == 2) ? csarr[2] : csel;
    csel = (tid == 3) ? csarr[3] : csel;
    csel = (tid == 4) ? csarr[4] : csel;
    csel = (tid == 5) ? csarr[5] : csel;

    float acc[kM], mwacc[kM];
#pragma unroll
    for (int m = 0; m < kM; ++m) { acc[m] = 0.f; mwacc[m] = 0.f; }
    float lossacc = 0.f;

    int r = start;
    while (r < end) {
        const int rem = end - r;
        const int cnt = rem < 4 ? rem : 4;
        int   rows[4];
        float dvv[4], bet[4];
#pragma unroll
        for (int i = 0; i < 4; ++i) if (i < cnt) rows[i] = order[r + i];
#pragma unroll
        for (int i = 0; i < 4; ++i) if (i < cnt) {
            dvv[i] = data[(size_t)rows[i] * kD + tid];
            bet[i] = beta[rows[i]];
        }
#pragma unroll
        for (int i = 0; i < 4; ++i) if (i < cnt) {
            float nw[kM];
            float wsumv = 0.f;
#pragma unroll
            for (int m = 0; m < kM; ++m) {
                const float dvb = bet[i] - csarr[m];
                const float wv = expf(-sqrtf(dvb * dvb + 1e-10f));
                nw[m] = wv;
                wsumv += wv;
            }
            const float inv = 1.f / (wsumv + kEPS + 1e-10f);
            float cm = 0.f;
#pragma unroll
            for (int m = 0; m < kM; ++m) {
                const float w = nw[m] * inv;
                cm       += w * cv[m];
                acc[m]   += w * dvv[i];
                mwacc[m] += w;
            }
            const float ax = dvv[i] - cm;
            lossacc += ax * ax;
            if (tid < kM) sum_v[rows[i] * kM + tid] = csel;
        }
        r += 4;
    }

    // mem_out = memory + acc (full coverage: every label, every element)
#pragma unroll
    for (int m = 0; m < kM; ++m)
        mem_out[cbase + (size_t)m * kD] = mv[m] + acc[m];

    // mw_out (threads 0..5; mwacc is block-uniform)
    float msel = mwacc[0];
    msel = (tid == 1) ? mwacc[1] : msel;
    msel = (tid == 2) ? mwacc[2] : msel;
    msel = (tid == 3) ? mwacc[3] : msel;
    msel = (tid == 4) ? mwacc[4] : msel;
    msel = (tid == 5) ? mwacc[5] : msel;
    if (tid < kM) {
        const size_t i = (size_t)lab * kM + tid;
        mw_out[i] = memw[i] + msel;
    }

    // loss: wave shuffle -> LDS -> one low-contention atomic per block
#pragma unroll
    for (int off = 32; off > 0; off >>= 1) lossacc += __shfl_down(lossacc, off, 64);
    if (lane == 0) ls[wid] = lossacc;
    __syncthreads();
    if (tid == 0)
        atomicAdd(partial + (lab & (kNPart - 1)), ls[0] + ls[1] + ls[2] + ls[3]);
}

// ---------- Kernel 5: final loss reduction (one wave) -----------------------
__global__ __launch_bounds__(64) void k_loss(
    const float* __restrict__ partial,
    float* __restrict__ loss_out)
{
    float s = 0.f;
#pragma unroll
    for (int i = 0; i < kNPart / 64; ++i) s += partial[i * 64 + threadIdx.x];
#pragma unroll
    for (int off = 32; off > 0; off >>= 1) s += __shfl_down(s, off, 64);
    if (threadIdx.x == 0) *loss_out = s * (1.f / ((float)kBS * (float)kD));
}

extern "C" void kernel_launch(void* const* d_in, const int* in_sizes, int n_in,
                              void* d_out, int out_size, void* d_ws, size_t ws_size,
                              hipStream_t stream) {
    const float* data    = (const float*)d_in[0];
    const int*   labels  = (const int*)  d_in[1];
    const float* beta    = (const float*)d_in[2];
    const float* centers = (const float*)d_in[3];
    const float* W1      = (const float*)d_in[4];
    const float* b1      = (const float*)d_in[5];
    const float* W2      = (const float*)d_in[6];
    const float* b2      = (const float*)d_in[7];
    const float* memory  = (const float*)d_in[8];
    const float* memw    = (const float*)d_in[9];

    float* out     = (float*)d_out;
    float* loss    = out;                                   // [1]
    float* sum_v   = out + 1;                               // [BS*M]
    float* mem_out = out + 1 + (size_t)kBS * kM;            // [C*M*D]
    float* mw_out  = mem_out + (size_t)kC * kM * kD;        // [C*M]

    // workspace layout: offs[C] | partial[kNPart] | order[BS]
    int*   offs    = (int*)d_ws;
    float* partial = (float*)(offs + kC);
    int*   order   = (int*)(partial + kNPart);

    // zero offs + partial in one shot (contiguous)
    hipMemsetAsync(d_ws, 0, (kC + kNPart) * sizeof(int), stream);

    k_count  <<<dim3(kBS / 256), dim3(256), 0, stream>>>(labels, offs);
    k_scan   <<<dim3(1),         dim3(256), 0, stream>>>(offs);
    k_scatter<<<dim3(kBS / 256), dim3(256), 0, stream>>>(labels, offs, order);
    k_agg    <<<dim3(kC),        dim3(256), 0, stream>>>(
        data, beta, offs, order, W1, b1, W2, b2,
        centers, memory, memw, partial, sum_v, mem_out, mw_out);
    k_loss   <<<dim3(1),         dim3(64),  0, stream>>>(partial, loss);
}